// Round 1
// baseline (227.761 us; speedup 1.0000x reference)
//
#include <hip/hip_runtime.h>
#include <hip/hip_bf16.h>
#include <stdint.h>

typedef unsigned short u16;
typedef float f32x4 __attribute__((ext_vector_type(4)));
typedef short bf16x8 __attribute__((ext_vector_type(8)));

#define NSP 4096      // H*W
#define CDIM 256
#define HID 256
#define NH 8
#define DH 32
#define NG 32
#define CPG 8
#define BATCH 2
#define GN_EPS 1e-5f
#define QK_SCALE 0.4204482076268573f  // 32^-0.25

__device__ __forceinline__ float bf2f(u16 u) {
    union { uint32_t i; float f; } v; v.i = ((uint32_t)u) << 16; return v.f;
}
__device__ __forceinline__ u16 f2bf(float f) {
    union { float f; uint32_t i; } v; v.f = f;
    uint32_t b = v.i;
    return (u16)((b + 0x7FFFu + ((b >> 16) & 1u)) >> 16);
}

// ---------------- weight fp32 -> bf16 ----------------
__global__ void cvt_w(const float* __restrict__ a, const float* __restrict__ b,
                      const float* __restrict__ c, const float* __restrict__ d,
                      u16* __restrict__ o) {
    int i = blockIdx.x * 256 + threadIdx.x;   // 65536 per matrix
    o[i]          = f2bf(a[i]);
    o[i + 65536]  = f2bf(b[i]);
    o[i + 131072] = f2bf(c[i]);
    o[i + 196608] = f2bf(d[i]);
}

// ---------------- GroupNorm stats: one block per (b,g) ----------------
__global__ void gn_stats(const float* __restrict__ x, float* __restrict__ stats) {
    int blk = blockIdx.x;  // b*NG + g ; group data is 32768 contiguous floats
    const float4* base = (const float4*)(x + (size_t)blk * (CPG * NSP));
    float s = 0.f, ss = 0.f;
    for (int i = threadIdx.x; i < (CPG * NSP) / 4; i += 256) {
        float4 v = base[i];
        s  += v.x + v.y + v.z + v.w;
        ss += v.x * v.x + v.y * v.y + v.z * v.z + v.w * v.w;
    }
    for (int m = 1; m < 64; m <<= 1) { s += __shfl_xor(s, m, 64); ss += __shfl_xor(ss, m, 64); }
    __shared__ float ls[4], lss[4];
    int w = threadIdx.x >> 6;
    if ((threadIdx.x & 63) == 0) { ls[w] = s; lss[w] = ss; }
    __syncthreads();
    if (threadIdx.x == 0) {
        float S = ls[0] + ls[1] + ls[2] + ls[3];
        float SS = lss[0] + lss[1] + lss[2] + lss[3];
        float mean = S / (float)(CPG * NSP);
        float var = SS / (float)(CPG * NSP) - mean * mean;
        stats[2 * blk] = mean;
        stats[2 * blk + 1] = rsqrtf(var + GN_EPS);
    }
}

// ---------------- GN apply + transpose to (b, n, c) bf16 ----------------
__global__ void gn_apply(const float* __restrict__ x, const float* __restrict__ stats,
                         const float* __restrict__ gamma, const float* __restrict__ beta,
                         u16* __restrict__ xn) {
    __shared__ u16 tile[64][72];
    int n0 = blockIdx.x * 64, c0 = blockIdx.y * 64, b = blockIdx.z;
    int t = threadIdx.x;
    int nl = t & 63, cq = t >> 6;
#pragma unroll
    for (int i = 0; i < 16; i++) {
        int cl = i * 4 + cq;
        int c = c0 + cl;
        int g = c >> 3;
        float mean = stats[2 * (b * NG + g)];
        float rstd = stats[2 * (b * NG + g) + 1];
        float v = x[((size_t)b * CDIM + c) * NSP + n0 + nl];
        v = (v - mean) * rstd * gamma[c] + beta[c];
        tile[cl][nl] = f2bf(v);
    }
    __syncthreads();
    int nr = t >> 2, cc = (t & 3) * 16;
    uint4 o0, o1;
    u16* p0 = (u16*)&o0; u16* p1 = (u16*)&o1;
#pragma unroll
    for (int j = 0; j < 8; j++) { p0[j] = tile[cc + j][nr]; p1[j] = tile[cc + 8 + j][nr]; }
    size_t orow = ((size_t)b * NSP + n0 + nr) * CDIM + c0 + cc;
    *(uint4*)(xn + orow) = o0;
    *(uint4*)(xn + orow + 8) = o1;
}

// ---------------- generic bf16 GEMM: C[M,N] = A(MxK) * B(NxK)^T ----------------
// MODE 0: out_bf16[r*N+c] = (acc + bias[c]) * scale        (q/k proj)
// MODE 1: out_bf16[r*N+c] = acc + bias[r]                  (v proj, transposed out)
// MODE 2: out_f32 [r*N+c] = acc + bias[r] + resid[r*N+c]   (final proj + residual)
template <int MODE>
__global__ __launch_bounds__(256) void gemm_bt(
    const u16* __restrict__ A, long sA,
    const u16* __restrict__ B, long sB,
    const float* __restrict__ bias,
    const float* __restrict__ resid, long sR,
    void* __restrict__ outp, long sO,
    int M, int N, int K, float scale) {
    __shared__ u16 As[64][72];
    __shared__ u16 Bs[64][72];
    int bz = blockIdx.z;
    A += (size_t)bz * sA;
    B += (size_t)bz * sB;
    int m0 = blockIdx.y * 64, n0 = blockIdx.x * 64;
    int t = threadIdx.x, lane = t & 63, w = t >> 6;
    int wm = (w >> 1) * 32, wn = (w & 1) * 32;
    f32x4 acc[2][2] = {};

    int sr = t >> 2;
    int sc1 = (t & 3) * 8, sc2 = sc1 + 32;

    uint4 av0 = *(const uint4*)(A + (size_t)(m0 + sr) * K + sc1);
    uint4 av1 = *(const uint4*)(A + (size_t)(m0 + sr) * K + sc2);
    uint4 bv0 = *(const uint4*)(B + (size_t)(n0 + sr) * K + sc1);
    uint4 bv1 = *(const uint4*)(B + (size_t)(n0 + sr) * K + sc2);

    for (int k0 = 0; k0 < K; k0 += 64) {
        __syncthreads();
        *(uint4*)&As[sr][sc1] = av0;
        *(uint4*)&As[sr][sc2] = av1;
        *(uint4*)&Bs[sr][sc1] = bv0;
        *(uint4*)&Bs[sr][sc2] = bv1;
        __syncthreads();
        if (k0 + 64 < K) {
            av0 = *(const uint4*)(A + (size_t)(m0 + sr) * K + k0 + 64 + sc1);
            av1 = *(const uint4*)(A + (size_t)(m0 + sr) * K + k0 + 64 + sc2);
            bv0 = *(const uint4*)(B + (size_t)(n0 + sr) * K + k0 + 64 + sc1);
            bv1 = *(const uint4*)(B + (size_t)(n0 + sr) * K + k0 + 64 + sc2);
        }
#pragma unroll
        for (int ks = 0; ks < 2; ks++) {
            bf16x8 af[2], bfr[2];
#pragma unroll
            for (int i = 0; i < 2; i++) {
                af[i]  = *(bf16x8*)&As[wm + i * 16 + (lane & 15)][ks * 32 + (lane >> 4) * 8];
                bfr[i] = *(bf16x8*)&Bs[wn + i * 16 + (lane & 15)][ks * 32 + (lane >> 4) * 8];
            }
#pragma unroll
            for (int i = 0; i < 2; i++)
#pragma unroll
                for (int j = 0; j < 2; j++)
                    acc[i][j] = __builtin_amdgcn_mfma_f32_16x16x32_bf16(af[i], bfr[j], acc[i][j], 0, 0, 0);
        }
    }

    int r4 = (lane >> 4) * 4, cx = lane & 15;
#pragma unroll
    for (int i = 0; i < 2; i++)
#pragma unroll
        for (int j = 0; j < 2; j++) {
            int rbase = m0 + wm + i * 16 + r4;
            int cbase = n0 + wn + j * 16 + cx;
#pragma unroll
            for (int r = 0; r < 4; r++) {
                int row = rbase + r, col = cbase;
                float vv = acc[i][j][r];
                if (MODE == 0) {
                    vv = (vv + bias[col]) * scale;
                    ((u16*)outp)[(size_t)bz * sO + (size_t)row * N + col] = f2bf(vv);
                } else if (MODE == 1) {
                    vv = vv + bias[row];
                    ((u16*)outp)[(size_t)bz * sO + (size_t)row * N + col] = f2bf(vv);
                } else {
                    vv = vv + bias[row] + resid[(size_t)bz * sR + (size_t)row * N + col];
                    ((float*)outp)[(size_t)bz * sO + (size_t)row * N + col] = vv;
                }
            }
        }
}

// ---------------- flash attention ----------------
// q,k: (b, n, 256) bf16 (already scaled); v: (b, 256, n) bf16; out ao: (b, n, 256) bf16
__global__ __launch_bounds__(256) void attn_kernel(
    const u16* __restrict__ q, const u16* __restrict__ k,
    const u16* __restrict__ v, u16* __restrict__ ao) {
    __shared__ u16 Ks[64][40];
    __shared__ u16 Vs[32][72];
    __shared__ u16 Ps[4][16][72];
    int h = blockIdx.y, b = blockIdx.z;
    int t = threadIdx.x, lane = t & 63, w = t >> 6;
    int q0 = blockIdx.x * 64 + w * 16;
    const u16* qb = q + (size_t)b * NSP * HID;
    const u16* kb = k + (size_t)b * NSP * HID;
    const u16* vbp = v + (size_t)b * HID * NSP + (size_t)(h * DH) * NSP;

    bf16x8 qf = *(const bf16x8*)(qb + (size_t)(q0 + (lane & 15)) * HID + h * DH + (lane >> 4) * 8);

    f32x4 oacc[2] = {};
    float mrow[4] = {-3e38f, -3e38f, -3e38f, -3e38f};
    float lrow[4] = {0.f, 0.f, 0.f, 0.f};

    int kr = t >> 2, kc = (t & 3) * 8;
    int vr = t >> 3, vc = (t & 7) * 8;
    uint4 kreg = *(const uint4*)(kb + (size_t)kr * HID + h * DH + kc);
    uint4 vreg = *(const uint4*)(vbp + (size_t)vr * NSP + vc);

    for (int it = 0; it < NSP / 64; ++it) {
        __syncthreads();
        *(uint4*)&Ks[kr][kc] = kreg;
        *(uint4*)&Vs[vr][vc] = vreg;
        __syncthreads();
        if (it + 1 < NSP / 64) {
            int kn = (it + 1) * 64;
            kreg = *(const uint4*)(kb + (size_t)(kn + kr) * HID + h * DH + kc);
            vreg = *(const uint4*)(vbp + (size_t)vr * NSP + kn + vc);
        }
        // S = Q * K^T : 16x64 in 4 C-tiles
        f32x4 s[4];
#pragma unroll
        for (int ti = 0; ti < 4; ti++) {
            bf16x8 kf = *(bf16x8*)&Ks[ti * 16 + (lane & 15)][(lane >> 4) * 8];
            f32x4 z = {};
            s[ti] = __builtin_amdgcn_mfma_f32_16x16x32_bf16(qf, kf, z, 0, 0, 0);
        }
        // online softmax
#pragma unroll
        for (int r = 0; r < 4; r++) {
            float m = fmaxf(fmaxf(s[0][r], s[1][r]), fmaxf(s[2][r], s[3][r]));
#pragma unroll
            for (int msk = 1; msk < 16; msk <<= 1) m = fmaxf(m, __shfl_xor(m, msk, 64));
            float mn = fmaxf(mrow[r], m);
            float corr = __expf(mrow[r] - mn);
            mrow[r] = mn;
            float rs = 0.f;
#pragma unroll
            for (int ti = 0; ti < 4; ti++) {
                float p = __expf(s[ti][r] - mn);
                s[ti][r] = p;
                rs += p;
            }
#pragma unroll
            for (int msk = 1; msk < 16; msk <<= 1) rs += __shfl_xor(rs, msk, 64);
            lrow[r] = lrow[r] * corr + rs;
            oacc[0][r] *= corr;
            oacc[1][r] *= corr;
        }
        // P -> LDS (per-wave buffer), bf16
#pragma unroll
        for (int ti = 0; ti < 4; ti++)
#pragma unroll
            for (int r = 0; r < 4; r++)
                Ps[w][(lane >> 4) * 4 + r][ti * 16 + (lane & 15)] = f2bf(s[ti][r]);
        // O += P * V^T
#pragma unroll
        for (int ks = 0; ks < 2; ks++) {
            bf16x8 pf = *(bf16x8*)&Ps[w][lane & 15][ks * 32 + (lane >> 4) * 8];
#pragma unroll
            for (int dt = 0; dt < 2; dt++) {
                bf16x8 vf = *(bf16x8*)&Vs[dt * 16 + (lane & 15)][ks * 32 + (lane >> 4) * 8];
                oacc[dt] = __builtin_amdgcn_mfma_f32_16x16x32_bf16(pf, vf, oacc[dt], 0, 0, 0);
            }
        }
    }
    // epilogue
    u16* aob = ao + (size_t)b * NSP * HID;
#pragma unroll
    for (int r = 0; r < 4; r++) {
        float inv = 1.0f / lrow[r];
        int row = q0 + (lane >> 4) * 4 + r;
#pragma unroll
        for (int dt = 0; dt < 2; dt++) {
            float val = oacc[dt][r] * inv;
            aob[(size_t)row * HID + h * DH + dt * 16 + (lane & 15)] = f2bf(val);
        }
    }
}

extern "C" void kernel_launch(void* const* d_in, const int* in_sizes, int n_in,
                              void* d_out, int out_size, void* d_ws, size_t ws_size,
                              hipStream_t stream) {
    const float* x     = (const float*)d_in[0];
    const float* gamma = (const float*)d_in[1];
    const float* beta  = (const float*)d_in[2];
    const float* wq    = (const float*)d_in[3];
    const float* bq    = (const float*)d_in[4];
    const float* wk    = (const float*)d_in[5];
    const float* bk    = (const float*)d_in[6];
    const float* wv    = (const float*)d_in[7];
    const float* bv    = (const float*)d_in[8];
    const float* wout  = (const float*)d_in[9];
    const float* bout  = (const float*)d_in[10];
    float* out = (float*)d_out;

    char* ws = (char*)d_ws;
    float* stats = (float*)ws;                       // 512 B
    u16* wq_b = (u16*)(ws + 4096);
    u16* wk_b = wq_b + 65536;
    u16* wv_b = wk_b + 65536;
    u16* wo_b = wv_b + 65536;
    u16* xn = wo_b + 65536;                          // (b,n,c) bf16
    u16* qb = xn + (size_t)BATCH * NSP * CDIM;       // (b,n,hid)
    u16* kb = qb + (size_t)BATCH * NSP * HID;        // (b,n,hid)
    u16* vb = kb + (size_t)BATCH * NSP * HID;        // (b,hid,n)
    u16* aob = vb + (size_t)BATCH * HID * NSP;       // (b,n,hid)

    const long sXN = (long)NSP * CDIM;
    const long sQ = (long)NSP * HID;
    const long sOut = (long)CDIM * NSP;

    cvt_w<<<256, 256, 0, stream>>>(wq, wk, wv, wout, wq_b);
    gn_stats<<<BATCH * NG, 256, 0, stream>>>(x, stats);
    gn_apply<<<dim3(NSP / 64, CDIM / 64, BATCH), 256, 0, stream>>>(x, stats, gamma, beta, xn);

    // q = xn * wq^T  (M=NSP, N=HID)
    gemm_bt<0><<<dim3(HID / 64, NSP / 64, BATCH), 256, 0, stream>>>(
        xn, sXN, wq_b, 0L, bq, nullptr, 0L, qb, sQ, NSP, HID, CDIM, QK_SCALE);
    gemm_bt<0><<<dim3(HID / 64, NSP / 64, BATCH), 256, 0, stream>>>(
        xn, sXN, wk_b, 0L, bk, nullptr, 0L, kb, sQ, NSP, HID, CDIM, QK_SCALE);
    // v^T = wv * xn^T (M=HID rows=o, N=NSP cols=n)
    gemm_bt<1><<<dim3(NSP / 64, HID / 64, BATCH), 256, 0, stream>>>(
        wv_b, 0L, xn, sXN, bv, nullptr, 0L, vb, (long)HID * NSP, HID, NSP, CDIM, 1.0f);

    attn_kernel<<<dim3(NSP / 64, NH, BATCH), 256, 0, stream>>>(qb, kb, vb, aob);

    // out = wout * ao^T + bout + x  (M=CDIM rows=o, N=NSP)
    gemm_bt<2><<<dim3(NSP / 64, CDIM / 64, BATCH), 256, 0, stream>>>(
        wo_b, 0L, aob, sQ, bout, x, sOut, out, sOut, CDIM, NSP, CDIM, 1.0f);
}

// Round 2
// 166.384 us; speedup vs baseline: 1.3689x; 1.3689x over previous
//
#include <hip/hip_runtime.h>
#include <hip/hip_bf16.h>
#include <stdint.h>

typedef unsigned short u16;
typedef float f32x4 __attribute__((ext_vector_type(4)));
typedef float f32x16 __attribute__((ext_vector_type(16)));
typedef short bf16x8 __attribute__((ext_vector_type(8)));

#define NSP 4096      // H*W
#define CDIM 256
#define HID 256
#define NH 8
#define DH 32
#define NG 32
#define CPG 8
#define BATCH 2
#define GN_EPS 1e-5f
// K side carries SCALE^2 * log2(e)  (exp2-domain softmax)
#define QK2_SCALE 0.25503488f

#define MFMA32(A, B, C) __builtin_amdgcn_mfma_f32_32x32x16_bf16(A, B, C, 0, 0, 0)

__device__ __forceinline__ u16 f2bf(float f) {
    union { float f; uint32_t i; } v; v.f = f;
    uint32_t b = v.i;
    return (u16)((b + 0x7FFFu + ((b >> 16) & 1u)) >> 16);
}

// ---------------- weight fp32 -> bf16 ----------------
__global__ void cvt_w(const float* __restrict__ a, const float* __restrict__ b,
                      const float* __restrict__ c, const float* __restrict__ d,
                      u16* __restrict__ o) {
    int i = blockIdx.x * 256 + threadIdx.x;
    o[i]          = f2bf(a[i]);
    o[i + 65536]  = f2bf(b[i]);
    o[i + 131072] = f2bf(c[i]);
    o[i + 196608] = f2bf(d[i]);
}

// ---------------- GroupNorm stats: one block per (b,g) ----------------
__global__ void gn_stats(const float* __restrict__ x, float* __restrict__ stats) {
    int blk = blockIdx.x;
    const float4* base = (const float4*)(x + (size_t)blk * (CPG * NSP));
    float s = 0.f, ss = 0.f;
    for (int i = threadIdx.x; i < (CPG * NSP) / 4; i += 256) {
        float4 v = base[i];
        s  += v.x + v.y + v.z + v.w;
        ss += v.x * v.x + v.y * v.y + v.z * v.z + v.w * v.w;
    }
    for (int m = 1; m < 64; m <<= 1) { s += __shfl_xor(s, m, 64); ss += __shfl_xor(ss, m, 64); }
    __shared__ float ls[4], lss[4];
    int w = threadIdx.x >> 6;
    if ((threadIdx.x & 63) == 0) { ls[w] = s; lss[w] = ss; }
    __syncthreads();
    if (threadIdx.x == 0) {
        float S = ls[0] + ls[1] + ls[2] + ls[3];
        float SS = lss[0] + lss[1] + lss[2] + lss[3];
        float mean = S / (float)(CPG * NSP);
        float var = SS / (float)(CPG * NSP) - mean * mean;
        stats[2 * blk] = mean;
        stats[2 * blk + 1] = rsqrtf(var + GN_EPS);
    }
}

// ---------------- GN apply + transpose to (b, n, c) bf16 ----------------
__global__ void gn_apply(const float* __restrict__ x, const float* __restrict__ stats,
                         const float* __restrict__ gamma, const float* __restrict__ beta,
                         u16* __restrict__ xn) {
    __shared__ u16 tile[64][72];
    int n0 = blockIdx.x * 64, c0 = blockIdx.y * 64, b = blockIdx.z;
    int t = threadIdx.x;
    int nl = t & 63, cq = t >> 6;
#pragma unroll
    for (int i = 0; i < 16; i++) {
        int cl = i * 4 + cq;
        int c = c0 + cl;
        int g = c >> 3;
        float mean = stats[2 * (b * NG + g)];
        float rstd = stats[2 * (b * NG + g) + 1];
        float v = x[((size_t)b * CDIM + c) * NSP + n0 + nl];
        v = (v - mean) * rstd * gamma[c] + beta[c];
        tile[cl][nl] = f2bf(v);
    }
    __syncthreads();
    int nr = t >> 2, cc = (t & 3) * 16;
    uint4 o0, o1;
    u16* p0 = (u16*)&o0; u16* p1 = (u16*)&o1;
#pragma unroll
    for (int j = 0; j < 8; j++) { p0[j] = tile[cc + j][nr]; p1[j] = tile[cc + 8 + j][nr]; }
    size_t orow = ((size_t)b * NSP + n0 + nr) * CDIM + c0 + cc;
    *(uint4*)(xn + orow) = o0;
    *(uint4*)(xn + orow + 8) = o1;
}

// ---------------- generic bf16 GEMM: C[M,N] = A(MxK) * B(NxK)^T ----------------
template <int MODE>
__global__ __launch_bounds__(256) void gemm_bt(
    const u16* __restrict__ A, long sA,
    const u16* __restrict__ B, long sB,
    const float* __restrict__ bias,
    const float* __restrict__ resid, long sR,
    void* __restrict__ outp, long sO,
    int M, int N, int K, float scale) {
    __shared__ u16 As[64][72];
    __shared__ u16 Bs[64][72];
    int bz = blockIdx.z;
    A += (size_t)bz * sA;
    B += (size_t)bz * sB;
    int m0 = blockIdx.y * 64, n0 = blockIdx.x * 64;
    int t = threadIdx.x, lane = t & 63, w = t >> 6;
    int wm = (w >> 1) * 32, wn = (w & 1) * 32;
    f32x4 acc[2][2] = {};

    int sr = t >> 2;
    int sc1 = (t & 3) * 8, sc2 = sc1 + 32;

    uint4 av0 = *(const uint4*)(A + (size_t)(m0 + sr) * K + sc1);
    uint4 av1 = *(const uint4*)(A + (size_t)(m0 + sr) * K + sc2);
    uint4 bv0 = *(const uint4*)(B + (size_t)(n0 + sr) * K + sc1);
    uint4 bv1 = *(const uint4*)(B + (size_t)(n0 + sr) * K + sc2);

    for (int k0 = 0; k0 < K; k0 += 64) {
        __syncthreads();
        *(uint4*)&As[sr][sc1] = av0;
        *(uint4*)&As[sr][sc2] = av1;
        *(uint4*)&Bs[sr][sc1] = bv0;
        *(uint4*)&Bs[sr][sc2] = bv1;
        __syncthreads();
        if (k0 + 64 < K) {
            av0 = *(const uint4*)(A + (size_t)(m0 + sr) * K + k0 + 64 + sc1);
            av1 = *(const uint4*)(A + (size_t)(m0 + sr) * K + k0 + 64 + sc2);
            bv0 = *(const uint4*)(B + (size_t)(n0 + sr) * K + k0 + 64 + sc1);
            bv1 = *(const uint4*)(B + (size_t)(n0 + sr) * K + k0 + 64 + sc2);
        }
#pragma unroll
        for (int ks = 0; ks < 2; ks++) {
            bf16x8 af[2], bfr[2];
#pragma unroll
            for (int i = 0; i < 2; i++) {
                af[i]  = *(bf16x8*)&As[wm + i * 16 + (lane & 15)][ks * 32 + (lane >> 4) * 8];
                bfr[i] = *(bf16x8*)&Bs[wn + i * 16 + (lane & 15)][ks * 32 + (lane >> 4) * 8];
            }
#pragma unroll
            for (int i = 0; i < 2; i++)
#pragma unroll
                for (int j = 0; j < 2; j++)
                    acc[i][j] = __builtin_amdgcn_mfma_f32_16x16x32_bf16(af[i], bfr[j], acc[i][j], 0, 0, 0);
        }
    }

    int r4 = (lane >> 4) * 4, cx = lane & 15;
#pragma unroll
    for (int i = 0; i < 2; i++)
#pragma unroll
        for (int j = 0; j < 2; j++) {
            int rbase = m0 + wm + i * 16 + r4;
            int cbase = n0 + wn + j * 16 + cx;
#pragma unroll
            for (int r = 0; r < 4; r++) {
                int row = rbase + r, col = cbase;
                float vv = acc[i][j][r];
                if (MODE == 0) {
                    vv = (vv + bias[col]) * scale;
                    ((u16*)outp)[(size_t)bz * sO + (size_t)row * N + col] = f2bf(vv);
                } else if (MODE == 1) {
                    vv = vv + bias[row];
                    ((u16*)outp)[(size_t)bz * sO + (size_t)row * N + col] = f2bf(vv);
                } else {
                    vv = vv + bias[row] + resid[(size_t)bz * sR + (size_t)row * N + col];
                    ((float*)outp)[(size_t)bz * sO + (size_t)row * N + col] = vv;
                }
            }
        }
}

// ---------------- flash attention, swapped-QK^T 32x32 (m214 structure) ----------------
// q: (b,n,256) bf16 unscaled; k: (b,n,256) bf16 scaled by SCALE^2*log2e; v: (b,256,n) bf16
// Each wave owns 32 q-rows. No LDS staging, no barriers. S^T = mfma(K,Q):
// lane holds q = lane&31, k = (r&3)+8*(r>>2)+4*(lane>>5). Softmax per-lane + one xor-32 shuffle.
__global__ __launch_bounds__(256, 2) void attn_kernel(
    const u16* __restrict__ q, const u16* __restrict__ k,
    const u16* __restrict__ v, u16* __restrict__ ao) {
    __shared__ float Ls[4][32];
    int h = blockIdx.y, b = blockIdx.z;
    int t = threadIdx.x, lane = t & 63, w = t >> 6;
    int ql = lane & 31, hi = lane >> 5;
    bool hi0 = (hi == 0);
    int q0 = blockIdx.x * 128 + w * 32;

    const u16* qb = q + (size_t)b * NSP * HID + (size_t)(q0 + ql) * HID + h * DH + hi * 8;
    const u16* kb = k + (size_t)b * NSP * HID + (size_t)ql * HID + h * DH + hi * 8;
    const u16* vb = v + ((size_t)b * HID + h * DH + ql) * NSP + hi * 8;

    bf16x8 qf0 = *(const bf16x8*)(qb);
    bf16x8 qf1 = *(const bf16x8*)(qb + 16);

    f32x16 oacc = {};          // col d = ql, row q = crow(r,hi)
    float m = -1e30f, l = 0.f;

#define LOADK(dst, off) { \
    dst[0] = *(const bf16x8*)(kb + (size_t)(off) * HID);        \
    dst[1] = *(const bf16x8*)(kb + (size_t)(off) * HID + 16);   \
    dst[2] = *(const bf16x8*)(kb + (size_t)(off + 32) * HID);   \
    dst[3] = *(const bf16x8*)(kb + (size_t)(off + 32) * HID + 16); }
#define LOADV(dst, off) { \
    dst[0] = *(const bf16x8*)(vb + (off));      \
    dst[1] = *(const bf16x8*)(vb + (off) + 16); \
    dst[2] = *(const bf16x8*)(vb + (off) + 32); \
    dst[3] = *(const bf16x8*)(vb + (off) + 48); }

    auto process = [&](const bf16x8 (&kf)[4], const bf16x8 (&vf)[4]) {
#pragma unroll
        for (int tt = 0; tt < 2; tt++) {
            f32x16 st = {};
            st = MFMA32(kf[2 * tt], qf0, st);
            st = MFMA32(kf[2 * tt + 1], qf1, st);
            float pmax = st[0];
#pragma unroll
            for (int r = 1; r < 16; r++) pmax = fmaxf(pmax, st[r]);
            pmax = fmaxf(pmax, __shfl_xor(pmax, 32));
            if (!__all(pmax <= m + 8.f)) {          // defer-max (T13), log2 domain
                float mn = fmaxf(m, pmax);
                float corr = __builtin_amdgcn_exp2f(m - mn);
                l *= corr;
#pragma unroll
                for (int r = 0; r < 16; r++) oacc[r] *= corr;
                m = mn;
            }
            float p[16];
            float rs = 0.f;
#pragma unroll
            for (int r = 0; r < 16; r++) { p[r] = __builtin_amdgcn_exp2f(st[r] - m); rs += p[r]; }
            rs += __shfl_xor(rs, 32);
            l += rs;
            uint32_t pk[8];
#pragma unroll
            for (int j = 0; j < 8; j++) {
                uint32_t dd;
                asm("v_cvt_pk_bf16_f32 %0, %1, %2" : "=v"(dd) : "v"(p[2 * j]), "v"(p[2 * j + 1]));
                pk[j] = dd;
            }
            // P -> A-fragment (k = 8*hi + j within each 16-kv chunk)
#pragma unroll
            for (int c = 0; c < 2; c++) {
                uint32_t xs0 = __shfl_xor(pk[4 * c + 0], 32);
                uint32_t xs1 = __shfl_xor(pk[4 * c + 1], 32);
                uint32_t xs2 = __shfl_xor(pk[4 * c + 2], 32);
                uint32_t xs3 = __shfl_xor(pk[4 * c + 3], 32);
                union { uint32_t u[4]; bf16x8 v8; } fr;
                fr.u[0] = hi0 ? pk[4 * c + 0] : xs2;
                fr.u[1] = hi0 ? pk[4 * c + 1] : xs3;
                fr.u[2] = hi0 ? xs0 : pk[4 * c + 2];
                fr.u[3] = hi0 ? xs1 : pk[4 * c + 3];
                oacc = MFMA32(fr.v8, vf[2 * tt + c], oacc);
            }
        }
    };

    bf16x8 ka[4], va[4], kc[4], vc[4];
    LOADK(ka, 0); LOADV(va, 0);
    for (int it = 0; it < NSP / 64; it += 2) {
        int o1 = (it + 1) * 64;
        LOADK(kc, o1); LOADV(vc, o1);
        process(ka, va);
        int o2 = (it + 2 < NSP / 64) ? (it + 2) * 64 : 0;
        LOADK(ka, o2); LOADV(va, o2);
        process(kc, vc);
    }
#undef LOADK
#undef LOADV

    // epilogue: l lives at lane (q = ql); O rows are q = crow(r,hi)
    Ls[w][ql] = l;
    u16* aob = ao + (size_t)b * NSP * HID + h * DH + ql;
#pragma unroll
    for (int r = 0; r < 16; r++) {
        int qq = (r & 3) + 8 * (r >> 2) + 4 * hi;
        float ll = Ls[w][qq];
        aob[(size_t)(q0 + qq) * HID] = f2bf(oacc[r] / ll);
    }
}

extern "C" void kernel_launch(void* const* d_in, const int* in_sizes, int n_in,
                              void* d_out, int out_size, void* d_ws, size_t ws_size,
                              hipStream_t stream) {
    const float* x     = (const float*)d_in[0];
    const float* gamma = (const float*)d_in[1];
    const float* beta  = (const float*)d_in[2];
    const float* wq    = (const float*)d_in[3];
    const float* bq    = (const float*)d_in[4];
    const float* wk    = (const float*)d_in[5];
    const float* bk    = (const float*)d_in[6];
    const float* wv    = (const float*)d_in[7];
    const float* bv    = (const float*)d_in[8];
    const float* wout  = (const float*)d_in[9];
    const float* bout  = (const float*)d_in[10];
    float* out = (float*)d_out;

    char* ws = (char*)d_ws;
    float* stats = (float*)ws;
    u16* wq_b = (u16*)(ws + 4096);
    u16* wk_b = wq_b + 65536;
    u16* wv_b = wk_b + 65536;
    u16* wo_b = wv_b + 65536;
    u16* xn = wo_b + 65536;                          // (b,n,c) bf16
    u16* qb = xn + (size_t)BATCH * NSP * CDIM;       // (b,n,hid)
    u16* kb = qb + (size_t)BATCH * NSP * HID;        // (b,n,hid)
    u16* vb = kb + (size_t)BATCH * NSP * HID;        // (b,hid,n)
    u16* aob = vb + (size_t)BATCH * HID * NSP;       // (b,n,hid)

    const long sXN = (long)NSP * CDIM;
    const long sQ = (long)NSP * HID;
    const long sOut = (long)CDIM * NSP;

    cvt_w<<<256, 256, 0, stream>>>(wq, wk, wv, wout, wq_b);
    gn_stats<<<BATCH * NG, 256, 0, stream>>>(x, stats);
    gn_apply<<<dim3(NSP / 64, CDIM / 64, BATCH), 256, 0, stream>>>(x, stats, gamma, beta, xn);

    // q = xn * wq^T (unscaled); k = xn * wk^T scaled by SCALE^2*log2e
    gemm_bt<0><<<dim3(HID / 64, NSP / 64, BATCH), 256, 0, stream>>>(
        xn, sXN, wq_b, 0L, bq, nullptr, 0L, qb, sQ, NSP, HID, CDIM, 1.0f);
    gemm_bt<0><<<dim3(HID / 64, NSP / 64, BATCH), 256, 0, stream>>>(
        xn, sXN, wk_b, 0L, bk, nullptr, 0L, kb, sQ, NSP, HID, CDIM, QK2_SCALE);
    // v^T = wv * xn^T
    gemm_bt<1><<<dim3(NSP / 64, HID / 64, BATCH), 256, 0, stream>>>(
        wv_b, 0L, xn, sXN, bv, nullptr, 0L, vb, (long)HID * NSP, HID, NSP, CDIM, 1.0f);

    attn_kernel<<<dim3(NSP / 128, NH, BATCH), 256, 0, stream>>>(qb, kb, vb, aob);

    // out = wout * ao^T + bout + x
    gemm_bt<2><<<dim3(NSP / 64, CDIM / 64, BATCH), 256, 0, stream>>>(
        wo_b, 0L, aob, sQ, bout, x, sOut, out, sOut, CDIM, NSP, CDIM, 1.0f);
}